// Round 9
// baseline (119.741 us; speedup 1.0000x reference)
//
#include <hip/hip_runtime.h>
#include <hip/hip_bf16.h>

// ChebConv_17841294148274. f32 in / f32 out (verified r3).
// out[(r*8+g)*192+j'] = sum_k Z[r][g][k]*W2[k][j'] + bias,
// Z[r][g][k] = sum_{e in row r} val_e * x_flat[col_e*512 + g*64 + k].
#define NV      2048          // n_vertex
#define NNZ_    98304
#define KDIM    64            // contraction dim
#define WCOLS   192           // Ks*c_out
#define ZROWS   16384         // NV * 8
#define BUCKET  128           // slots per row (Poisson(48) -> overflow ~1e-20)
#define XCONV_BLKS 768        // 3,145,728 f32 / (256 thr * 16 f32)

typedef __attribute__((ext_vector_type(8))) short  short8;
typedef __attribute__((ext_vector_type(8))) unsigned short ushort8;
typedef __attribute__((ext_vector_type(4))) float  float4v;

__device__ __forceinline__ float b2f(unsigned short h) {
    return __uint_as_float(((unsigned int)h) << 16);
}
__device__ __forceinline__ unsigned short f2b(float f) {
    return __bfloat16_as_ushort(__float2bfloat16(f));
}

// ---- Prep kernel: X->bf16 (blocks 0..767), edge scatter (768..863), W^T (864)
__global__ __launch_bounds__(256) void scatter_kernel(
    const int4* __restrict__ rows4, const int4* __restrict__ cols4,
    const float4* __restrict__ vals4, const float* __restrict__ wf,
    const float4* __restrict__ x4,
    int* __restrict__ cnt, int2* __restrict__ sedge,
    unsigned short* __restrict__ wt, unsigned short* __restrict__ xh)
{
    const int b = blockIdx.x;
    if (b < XCONV_BLKS) {
        // convert 16 f32/thread -> two ushort8 stores
        const int base = (b * 256 + threadIdx.x) * 4;     // float4 index
        const float4 v0 = x4[base], v1 = x4[base + 1];
        const float4 v2 = x4[base + 2], v3 = x4[base + 3];
        ushort8 p0, p1;
        p0[0]=f2b(v0.x); p0[1]=f2b(v0.y); p0[2]=f2b(v0.z); p0[3]=f2b(v0.w);
        p0[4]=f2b(v1.x); p0[5]=f2b(v1.y); p0[6]=f2b(v1.z); p0[7]=f2b(v1.w);
        p1[0]=f2b(v2.x); p1[1]=f2b(v2.y); p1[2]=f2b(v2.z); p1[3]=f2b(v2.w);
        p1[4]=f2b(v3.x); p1[5]=f2b(v3.y); p1[6]=f2b(v3.z); p1[7]=f2b(v3.w);
        *(ushort8*)(xh + base * 4)     = p0;
        *(ushort8*)(xh + base * 4 + 8) = p1;
        return;
    }
    if (b == XCONV_BLKS + NNZ_ / 1024) {
        // wt[n*64+k] = bf16(W2[k][n]); W2 flat [64][192].
        for (int i = 0; i < 48; i++) {
            const int e = threadIdx.x + 256 * i;       // [0,12288)
            const int k = e / WCOLS, n = e - k * WCOLS;
            wt[n * KDIM + k] = f2b(wf[e]);
        }
        return;
    }
    const int t = (b - XCONV_BLKS) * 256 + threadIdx.x;   // [0, 24576)
    const int4   r = rows4[t];
    const int4   c = cols4[t];
    const float4 v = vals4[t];
    int p;
    p = atomicAdd(&cnt[r.x], 1); if (p < BUCKET) sedge[r.x * BUCKET + p] = make_int2(c.x * 512, __float_as_int(v.x));
    p = atomicAdd(&cnt[r.y], 1); if (p < BUCKET) sedge[r.y * BUCKET + p] = make_int2(c.y * 512, __float_as_int(v.y));
    p = atomicAdd(&cnt[r.z], 1); if (p < BUCKET) sedge[r.z * BUCKET + p] = make_int2(c.z * 512, __float_as_int(v.z));
    p = atomicAdd(&cnt[r.w], 1); if (p < BUCKET) sedge[r.w * BUCKET + p] = make_int2(c.w * 512, __float_as_int(v.w));
}

// ---- Stage 1: sparse gather on bf16 X. 4096 blocks x 4 waves; wave-unit =
// (row,g). g = blk&7 pins each g-slab to one XCD (slab set = 1.57MB < 4MB L2).
// Lane k owns Z[r][g][k]: per edge one 128B wave-load. Edges read 2-at-a-time
// via int4; unroll x8.
__global__ __launch_bounds__(256) void spmmx_kernel(
    const unsigned short* __restrict__ xh,
    const int* __restrict__ cnt,
    const int2* __restrict__ sedge,
    unsigned short* __restrict__ zb)       // Z as bf16 [16384][64]
{
    const int b    = blockIdx.x;
    const int g    = b & 7;
    const int row  = (b >> 3) * 4 + (threadIdx.x >> 6);
    const int lane = threadIdx.x & 63;

    int n = cnt[row];
    if (n > BUCKET) n = BUCKET;
    const int4* se2 = (const int4*)(sedge + row * BUCKET);   // 2 edges per int4
    const int off = g * KDIM + lane;

    float acc = 0.f;
    int i = 0;
    for (; i + 8 <= n; i += 8) {
        const int4 ea = se2[(i >> 1)    ];
        const int4 eb = se2[(i >> 1) + 1];
        const int4 ec = se2[(i >> 1) + 2];
        const int4 ed = se2[(i >> 1) + 3];
        const float x0 = b2f(xh[ea.x + off]), x1 = b2f(xh[ea.z + off]);
        const float x2 = b2f(xh[eb.x + off]), x3 = b2f(xh[eb.z + off]);
        const float x4v = b2f(xh[ec.x + off]), x5 = b2f(xh[ec.z + off]);
        const float x6 = b2f(xh[ed.x + off]), x7 = b2f(xh[ed.z + off]);
        acc += __int_as_float(ea.y) * x0 + __int_as_float(ea.w) * x1
             + __int_as_float(eb.y) * x2 + __int_as_float(eb.w) * x3
             + __int_as_float(ec.y) * x4v + __int_as_float(ec.w) * x5
             + __int_as_float(ed.y) * x6 + __int_as_float(ed.w) * x7;
    }
    const int2* se = (const int2*)se2;
    for (; i < n; i++) {
        const int2 e = se[i];
        acc += __int_as_float(e.y) * b2f(xh[e.x + off]);
    }
    zb[(size_t)(row * 8 + g) * KDIM + lane] = f2b(acc);
}

// ---- Stage 2 GEMM via MFMA: out[m][j'] = sum_k Z[m][k] W2[k][j'] + bias ----
// 256 blocks x 256 thr (4 waves). Block = 64 m-rows x 192 cols, K=64.
// LDS rows padded to 72 shorts -> 2-way bank aliasing only (free).
// Frags (HW-verified m89/m91): A[m=lane&15][k=(lane>>4)*8+j]; B same with
// n=lane&15; C/D col=lane&15, row=(lane>>4)*4+reg.
__global__ __launch_bounds__(256) void gemm2_kernel(
    const unsigned short* __restrict__ zb, const unsigned short* __restrict__ wt,
    const float* __restrict__ bias, float* __restrict__ out)
{
    __shared__ unsigned short Wt[WCOLS * 72];   // 192 x 72 = 27.6 KB
    __shared__ unsigned short Zs[64 * 72];      //  64 x 72 =  9.2 KB
    const int tid = threadIdx.x;
    const int m0  = blockIdx.x * 64;

#pragma unroll
    for (int u = 0; u < 2; u++) {   // stage Z-tile: 512 ushort8 chunks
        const int ch = tid + 256 * u;              // [0,512) -> 64 rows x 64 k
        const ushort8 p = *(const ushort8*)(zb + (size_t)m0 * KDIM + ch * 8);
        const int row = ch >> 3, col = (ch & 7) * 8;
        *(ushort8*)&Zs[row * 72 + col] = p;
    }
#pragma unroll
    for (int u = 0; u < 6; u++) {   // stage W^T: 1536 ushort8 chunks
        const int ch = tid + 256 * u;              // [0,1536) -> 192 rows x 64 k
        const ushort8 p = *(const ushort8*)(wt + ch * 8);
        const int row = ch >> 3, col = (ch & 7) * 8;
        *(ushort8*)&Wt[row * 72 + col] = p;
    }
    __syncthreads();

    const int lane = tid & 63;
    const int mt   = tid >> 6;          // wave id = m-tile 0..3
    const int q    = lane >> 4;         // quad 0..3
    const int c    = lane & 15;

    const short8 a0 = *(const short8*)&Zs[(mt * 16 + c) * 72 + q * 8];
    const short8 a1 = *(const short8*)&Zs[(mt * 16 + c) * 72 + 32 + q * 8];

    float4v acc[12];
#pragma unroll
    for (int nt = 0; nt < 12; nt++) {
        const short8 b0 = *(const short8*)&Wt[(nt * 16 + c) * 72 + q * 8];
        const short8 b1 = *(const short8*)&Wt[(nt * 16 + c) * 72 + 32 + q * 8];
        float4v d = {0.f, 0.f, 0.f, 0.f};
        d = __builtin_amdgcn_mfma_f32_16x16x32_bf16(a0, b0, d, 0, 0, 0);
        d = __builtin_amdgcn_mfma_f32_16x16x32_bf16(a1, b1, d, 0, 0, 0);
        acc[nt] = d;
    }

    const int rbase = m0 + mt * 16 + q * 4;
#pragma unroll
    for (int nt = 0; nt < 12; nt++) {
        const int col = nt * 16 + c;
        const float bb = bias[col & 63];
#pragma unroll
        for (int r = 0; r < 4; r++)
            out[(size_t)(rbase + r) * WCOLS + col] = acc[nt][r] + bb;
    }
}

extern "C" void kernel_launch(void* const* d_in, const int* in_sizes, int n_in,
                              void* d_out, int out_size, void* d_ws, size_t ws_size,
                              hipStream_t stream) {
    const float* x    = (const float*)d_in[0];
    const float* wgt  = (const float*)d_in[1];
    const float* bias = (const float*)d_in[2];
    const float* fval = (const float*)d_in[3];
    const int* frow   = (const int*)d_in[4];
    const int* fcol   = (const int*)d_in[5];

    // Workspace layout:
    int* cnt = (int*)d_ws;                                    // 2048 ints
    int2* sedge = (int2*)(cnt + 2048);                        // 2048*128 int2 = 2 MB
    unsigned short* wt = (unsigned short*)(sedge + NV * BUCKET); // 12288 bf16
    unsigned short* zb = wt + 12288;                          // 16384*64 bf16 = 2 MB
    unsigned short* xh = zb + (size_t)ZROWS * KDIM;           // 3,145,728 bf16 = 6.3 MB

    hipMemsetAsync(cnt, 0, 2048 * sizeof(int), stream);
    scatter_kernel<<<XCONV_BLKS + NNZ_ / 1024 + 1, 256, 0, stream>>>(
        (const int4*)frow, (const int4*)fcol, (const float4*)fval, wgt,
        (const float4*)x, cnt, sedge, wt, xh);
    spmmx_kernel <<<ZROWS / 4, 256, 0, stream>>>(xh, cnt, sedge, zb);
    gemm2_kernel <<<ZROWS / 64, 256, 0, stream>>>(zb, wt, bias, (float*)d_out);
}